// Round 7
// baseline (110.518 us; speedup 1.0000x reference)
//
#include <hip/hip_runtime.h>
#include <hip/hip_bf16.h>

typedef unsigned int u32;
typedef __attribute__((ext_vector_type(8))) _Float16 f16x8;
typedef __attribute__((ext_vector_type(4))) float f32x4;

#define GMIN_ 0.01f
#define GMAX_ 10.0f

// fast tanh(y) given y2 = 2*y :  tanh(y) = 1 - 2/(exp(2y)+1)
__device__ __forceinline__ float tanh_fast2(float y2) {
    float e = __expf(y2);
    float r = __builtin_amdgcn_rcpf(e + 1.0f);
    return fmaf(-2.0f, r, 1.0f);
}

// ---------------------------------------------------------------------------
// Prep v3: 16 blocks x 256 threads; block handles 16 output columns.
// Coalesced theta reads (16 consecutive n per 16 lanes), LDS transpose,
// coalesced W2t writes (1KB contiguous per column, 16 threads x 64B).
// W2t f16 [256 cols][512 K-interleaved]: [2k]=wp(k), [2k+1]=wn(k).
// Row 256 -> f32 bias (ones input); row 257 only feeds the norm sum.
// ---------------------------------------------------------------------------
__global__ __launch_bounds__(256) void prep_weights(
    const float* __restrict__ theta, const float* __restrict__ eta_inv,
    _Float16* __restrict__ W2t, float* __restrict__ bias)
{
    __shared__ float tile[258][17];      // clamped theta, padded
    __shared__ float psum[16][17];
    __shared__ float cinv[16];

    const int t  = threadIdx.x;
    const int kq = t >> 4;               // 0..15
    const int nl = t & 15;               // 0..15
    const int n  = blockIdx.x * 16 + nl;

    float part = 0.f;
#pragma unroll
    for (int i = 0; i < 17; ++i) {
        const int k = i * 16 + kq;
        if (k < 258) {
            float tt = theta[k * 256 + n];          // 16 consecutive n: coalesced
            tt = fminf(fmaxf(tt, -GMAX_), GMAX_);
            if (fabsf(tt) < GMIN_) tt = 0.f;
            tile[k][nl] = tt;
            part += fabsf(tt);
        }
    }
    psum[kq][nl] = part;
    __syncthreads();
    if (kq == 0) {
        float s = 0.f;
#pragma unroll
        for (int j = 0; j < 16; ++j) s += psum[j][nl];
        cinv[nl] = 1.0f / s;
    }
    __syncthreads();

    // write phase: thread = (nw, kc); writes 64B contiguous, 1KB per column
    const int nw = t >> 4;               // column-local 0..15
    const int kc = t & 15;               // k16-chunk 0..15
    const float inv = cinv[nw];
    const int nn = blockIdx.x * 16 + nw;
#pragma unroll
    for (int c = 0; c < 4; ++c) {
        f16x8 h;
#pragma unroll
        for (int e = 0; e < 4; ++e) {
            const float tt = tile[kc * 16 + c * 4 + e][nw];
            const float w  = fabsf(tt) * inv;
            const float wp = (tt >= 0.f) ? w : 0.f;
            h[2 * e]     = (_Float16)wp;
            h[2 * e + 1] = (_Float16)(w - wp);
        }
        *(f16x8*)(W2t + (size_t)nn * 512 + kc * 32 + c * 8) = h;
    }

    if (t < 16) {
        const float tt = tile[256][t];
        const float w  = fabsf(tt) * cinv[t];
        const float wp = (tt >= 0.f) ? w : 0.f;
        const float wn = w - wp;
        const float ei0 = eta_inv[0], ei1 = eta_inv[1], ei2 = eta_inv[2], ei3 = eta_inv[3];
        const float a1  = ei0 + ei1 * tanhf((1.0f - ei2) * ei3);
        bias[blockIdx.x * 16 + t] = wp + a1 * wn;
    }
}

// ---------------------------------------------------------------------------
// GEMM: block = 128 rows x 64 cols, 4 waves over m (wave 32x64).
// K split into 4 chunks of 128 f16; B reg-staged into double-buffered LDS
// (2 x 16KB, XOR slot swizzle), raw barriers only -- no vmcnt(0) drains, so
// the 1-deep A register prefetch survives every boundary.
// Grid = 256 mblk x 4 nblk = 1024 blocks = exactly 4 blocks/CU (50% occ).
// ---------------------------------------------------------------------------
__global__ __launch_bounds__(256, 4) void plax_gemm(
    const float* __restrict__ A, const _Float16* __restrict__ W2t,
    const float* __restrict__ bias, const float* __restrict__ eta_act,
    const float* __restrict__ eta_inv, float* __restrict__ out)
{
    __shared__ __align__(16) char Bs[2][16384];   // [buf][col 0..63][slot 0..15][16B]

    const int t    = threadIdx.x;
    const int bid  = blockIdx.x;
    // XCD chunks of 128; nblk fastest so the 4 n-blocks of one mblk share L2.
    const int swz  = ((bid & 7) << 7) | (bid >> 3);   // bijective, 1024 = 8*128
    const int mblk = swz >> 2;       // 0..255
    const int nblk = swz & 3;        // 0..3
    const int lane = t & 63, wave = t >> 6;
    const int lr   = lane & 15, lg = lane >> 4;

    const float ei0 = eta_inv[0], ei1 = eta_inv[1];
    const float k2i = 2.0f * eta_inv[3];
    const float c2i = 2.0f * eta_inv[2] * eta_inv[3];

    const int row0 = mblk * 128 + wave * 32;
    const int col0 = nblk * 64;

    const float* ap = A + (size_t)(row0 + lr) * 256 + lg * 4;

    // B stage mapping: idx = q*256 + t -> col = idx>>4 (0..63), slot = idx&15
    const _Float16* bsrc[4];
    char*           bdst[4];
#pragma unroll
    for (int q = 0; q < 4; ++q) {
        const int idx  = q * 256 + t;
        const int col  = idx >> 4;
        const int slot = idx & 15;
        bsrc[q] = W2t + (size_t)(col0 + col) * 512 + slot * 8;   // + r*128 later
        bdst[q] = (char*)&Bs[0][0] + col * 256 + ((slot ^ (col & 15)) * 16);
    }

    f32x4 acc[2][4] = {};

#define LDA(it, dst) do {                                         \
        dst[0] = *(const float4*)(ap + (it) * 16);                \
        dst[1] = *(const float4*)(ap + 4096 + (it) * 16);         \
    } while (0)

    float4 aqA[2], aqB[2];
    LDA(0, aqA);

    // ---- prologue: stage chunk 0 into Bs[0] ----
    f16x8 breg[4];
#pragma unroll
    for (int q = 0; q < 4; ++q) breg[q] = *(const f16x8*)(bsrc[q]);
#pragma unroll
    for (int q = 0; q < 4; ++q) *(f16x8*)(bdst[q]) = breg[q];
    asm volatile("s_waitcnt lgkmcnt(0)" ::: "memory");
    __builtin_amdgcn_sched_barrier(0);
    __builtin_amdgcn_s_barrier();

#pragma unroll
    for (int r = 0; r < 4; ++r) {
        // issue-early: next chunk's global loads (compiler-tracked vmcnt)
        if (r < 3) {
#pragma unroll
            for (int q = 0; q < 4; ++q)
                breg[q] = *(const f16x8*)(bsrc[q] + (r + 1) * 128);
        }

        const char* buf = (const char*)&Bs[r & 1][0];
#pragma unroll
        for (int j = 0; j < 4; ++j) {
            const int it = r * 4 + j;
            // 1-deep A prefetch (never drained: raw barriers only)
            if (it + 1 < 16) {
                if (it & 1) LDA(it + 1, aqA); else LDA(it + 1, aqB);
            }
            const float4* acur = (it & 1) ? aqB : aqA;

            f16x8 af[2];
#pragma unroll
            for (int m = 0; m < 2; ++m) {
                const float4 v = acur[m];
                f16x8 h;
                h[0] = (_Float16)v.x;
                h[1] = (_Float16)fmaf(ei1, tanh_fast2(fmaf(v.x, k2i, -c2i)), ei0);
                h[2] = (_Float16)v.y;
                h[3] = (_Float16)fmaf(ei1, tanh_fast2(fmaf(v.y, k2i, -c2i)), ei0);
                h[4] = (_Float16)v.z;
                h[5] = (_Float16)fmaf(ei1, tanh_fast2(fmaf(v.z, k2i, -c2i)), ei0);
                h[6] = (_Float16)v.w;
                h[7] = (_Float16)fmaf(ei1, tanh_fast2(fmaf(v.w, k2i, -c2i)), ei0);
                af[m] = h;
            }

            f16x8 bf[4];
#pragma unroll
            for (int n = 0; n < 4; ++n) {
                const int rr   = n * 16 + lr;
                const int phys = (j * 4 + lg) ^ (rr & 15);
                bf[n] = *(const f16x8*)(buf + rr * 256 + phys * 16);
            }

#pragma unroll
            for (int m = 0; m < 2; ++m)
#pragma unroll
                for (int n = 0; n < 4; ++n)
                    acc[m][n] = __builtin_amdgcn_mfma_f32_16x16x32_f16(
                        af[m], bf[n], acc[m][n], 0, 0, 0);
        }

        // publish next chunk: raw barriers, no vmcnt drain
        if (r < 3) {
            __builtin_amdgcn_s_barrier();          // all waves done reading buf^1
            const int off = ((r + 1) & 1) * 16384;
#pragma unroll
            for (int q = 0; q < 4; ++q)
                *(f16x8*)(bdst[q] + off) = breg[q];
            asm volatile("s_waitcnt lgkmcnt(0)" ::: "memory");
            __builtin_amdgcn_sched_barrier(0);
            __builtin_amdgcn_s_barrier();          // writes visible
        }
    }
#undef LDA

    // ---- epilogue: z = acc + bias ; out = ptanh_act(z) ----
    const float ea0 = eta_act[0], ea1 = eta_act[1];
    const float k2a = 2.0f * eta_act[3];
    const float c2a = 2.0f * eta_act[2] * eta_act[3];

    float bc[4];
#pragma unroll
    for (int n = 0; n < 4; ++n) bc[n] = bias[col0 + n * 16 + lr];

#pragma unroll
    for (int m = 0; m < 2; ++m) {
        const int rgb = row0 + m * 16 + lg * 4;
#pragma unroll
        for (int n = 0; n < 4; ++n) {
            const int cg = col0 + n * 16 + lr;
#pragma unroll
            for (int j = 0; j < 4; ++j) {
                const float z = acc[m][n][j] + bc[n];
                out[(size_t)(rgb + j) * 256 + cg] =
                    fmaf(ea1, tanh_fast2(fmaf(z, k2a, -c2a)), ea0);
            }
        }
    }
}

// ---------------------------------------------------------------------------
extern "C" void kernel_launch(void* const* d_in, const int* in_sizes, int n_in,
                              void* d_out, int out_size, void* d_ws, size_t ws_size,
                              hipStream_t stream) {
    (void)in_sizes; (void)n_in; (void)out_size; (void)ws_size;
    const float* a       = (const float*)d_in[0];
    const float* theta   = (const float*)d_in[1];
    const float* eta_act = (const float*)d_in[2];
    const float* eta_inv = (const float*)d_in[3];
    float* out = (float*)d_out;

    _Float16* W2t  = (_Float16*)d_ws;                        // 256 KiB
    float*    bias = (float*)((char*)d_ws + 256 * 512 * 2);  // 1 KiB

    prep_weights<<<16, 256, 0, stream>>>(theta, eta_inv, W2t, bias);
    plax_gemm<<<1024, 256, 0, stream>>>(a, W2t, bias, eta_act, eta_inv, out);
}

// Round 9
// 107.090 us; speedup vs baseline: 1.0320x; 1.0320x over previous
//
#include <hip/hip_runtime.h>
#include <hip/hip_bf16.h>

typedef unsigned int u32;
typedef __attribute__((ext_vector_type(8))) _Float16 f16x8;
typedef __attribute__((ext_vector_type(4))) float f32x4;

#define GMIN_ 0.01f
#define GMAX_ 10.0f
#define LOG2E_ 1.4426950408889634f

// tanh(y) with pre-scaled arg: given y2l = 2*y*log2(e),
// tanh(y) = 1 - 2/(exp2(y2l)+1). ~7 VALU ops incl. cvt.
__device__ __forceinline__ float tanh_exp2(float y2l) {
    float e = __builtin_amdgcn_exp2f(y2l);
    float r = __builtin_amdgcn_rcpf(e + 1.0f);
    return fmaf(-2.0f, r, 1.0f);
}

// ---------------------------------------------------------------------------
// Prep v3 (unchanged from R7, passed): 16 blocks x 256 threads; 16 cols/block.
// Coalesced theta reads, LDS transpose, coalesced W2t writes.
// W2t f16 [256 cols][512 K-interleaved]: [2k]=wp(k), [2k+1]=wn(k).
// Row 256 -> f32 bias (ones input); row 257 only feeds the norm sum.
// ---------------------------------------------------------------------------
__global__ __launch_bounds__(256) void prep_weights(
    const float* __restrict__ theta, const float* __restrict__ eta_inv,
    _Float16* __restrict__ W2t, float* __restrict__ bias)
{
    __shared__ float tile[258][17];
    __shared__ float psum[16][17];
    __shared__ float cinv[16];

    const int t  = threadIdx.x;
    const int kq = t >> 4;
    const int nl = t & 15;
    const int n  = blockIdx.x * 16 + nl;

    float part = 0.f;
#pragma unroll
    for (int i = 0; i < 17; ++i) {
        const int k = i * 16 + kq;
        if (k < 258) {
            float tt = theta[k * 256 + n];
            tt = fminf(fmaxf(tt, -GMAX_), GMAX_);
            if (fabsf(tt) < GMIN_) tt = 0.f;
            tile[k][nl] = tt;
            part += fabsf(tt);
        }
    }
    psum[kq][nl] = part;
    __syncthreads();
    if (kq == 0) {
        float s = 0.f;
#pragma unroll
        for (int j = 0; j < 16; ++j) s += psum[j][nl];
        cinv[nl] = 1.0f / s;
    }
    __syncthreads();

    const int nw = t >> 4;
    const int kc = t & 15;
    const float inv = cinv[nw];
    const int nn = blockIdx.x * 16 + nw;
#pragma unroll
    for (int c = 0; c < 4; ++c) {
        f16x8 h;
#pragma unroll
        for (int e = 0; e < 4; ++e) {
            const float tt = tile[kc * 16 + c * 4 + e][nw];
            const float w  = fabsf(tt) * inv;
            const float wp = (tt >= 0.f) ? w : 0.f;
            h[2 * e]     = (_Float16)wp;
            h[2 * e + 1] = (_Float16)(w - wp);
        }
        *(f16x8*)(W2t + (size_t)nn * 512 + kc * 32 + c * 8) = h;
    }

    if (t < 16) {
        const float tt = tile[256][t];
        const float w  = fabsf(tt) * cinv[t];
        const float wp = (tt >= 0.f) ? w : 0.f;
        const float wn = w - wp;
        const float ei0 = eta_inv[0], ei1 = eta_inv[1], ei2 = eta_inv[2], ei3 = eta_inv[3];
        const float a1  = ei0 + ei1 * tanhf((1.0f - ei2) * ei3);
        bias[blockIdx.x * 16 + t] = wp + a1 * wn;
    }
}

// ---------------------------------------------------------------------------
// GEMM R8: block = 128 rows x 64 cols, 4 waves over m (wave 32x64).
// K in 4 chunks of 128 f16. B: global_load_lds width-16 into double-buffered
// LDS (2 x 16KB), source pre-swizzled (slot ^= col&15) -> conflict-free
// ds_read_b128. Issue B(r+1) at chunk TOP; one vmcnt(0)+s_barrier per chunk
// at the END (B latency covered by the 4-iteration compute in between).
// A: 3-deep register prefetch, 4-slot statically-indexed buffer.
// Grid = 256 mblk x 4 nblk = 1024 blocks = 4 blocks/CU, 16 waves/CU.
// ---------------------------------------------------------------------------
__global__ __launch_bounds__(256, 4) void plax_gemm(
    const float* __restrict__ A, const _Float16* __restrict__ W2t,
    const float* __restrict__ bias, const float* __restrict__ eta_act,
    const float* __restrict__ eta_inv, float* __restrict__ out)
{
    __shared__ __align__(16) char Bs[2][16384];   // [buf][col 0..63][slot 0..15][16B]

    const int t    = threadIdx.x;
    const int bid  = blockIdx.x;
    const int swz  = ((bid & 7) << 7) | (bid >> 3);   // XCD-bijective, 1024 = 8*128
    const int mblk = swz >> 2;       // 0..255
    const int nblk = swz & 3;        // 0..3
    const int lane = t & 63, wave = t >> 6;
    const int lr   = lane & 15, lg = lane >> 4;

    const float ei0 = eta_inv[0], ei1 = eta_inv[1];
    const float k2i = 2.0f * eta_inv[3] * LOG2E_;
    const float c2i = 2.0f * eta_inv[2] * eta_inv[3] * LOG2E_;

    const int row0 = mblk * 128 + wave * 32;
    const int col0 = nblk * 64;

    const float* ap = A + (size_t)(row0 + lr) * 256 + lg * 4;

    // B stage source: thread t covers (col = i*16 + (t>>4), phys slot = t&15),
    // fetching logical slot (t&15)^(t>>4). Chunk r adds r*256 bytes.
    const char* bsrc = (const char*)W2t
        + (size_t)(col0 + (t >> 4)) * 1024
        + (size_t)(((t & 15) ^ (t >> 4)) * 16);

    f32x4 acc[2][4] = {};
    float4 aq[4][2];   // 4-slot A prefetch file; all indices compile-time

#define LDA(it_) do {                                               \
        aq[(it_) & 3][0] = *(const float4*)(ap + (it_) * 16);       \
        aq[(it_) & 3][1] = *(const float4*)(ap + 4096 + (it_) * 16);\
    } while (0)

#define STAGE_B(r_, bb_) do {                                                   \
        _Pragma("unroll")                                                       \
        for (int i_ = 0; i_ < 4; ++i_)                                          \
            __builtin_amdgcn_global_load_lds(                                   \
                (const __attribute__((address_space(1))) u32*)                  \
                    (bsrc + (size_t)i_ * 16384 + (size_t)(r_) * 256),           \
                (__attribute__((address_space(3))) u32*)                        \
                    ((char*)Bs + (bb_) * 16384 + i_ * 4096 + t * 16),           \
                16, 0, 0);                                                      \
    } while (0)

    // ---- prologue: stage chunk 0, hard-drain, then open the A pipeline ----
    STAGE_B(0, 0);
    asm volatile("s_waitcnt vmcnt(0)" ::: "memory");
    __builtin_amdgcn_sched_barrier(0);
    __builtin_amdgcn_s_barrier();
    LDA(0); LDA(1); LDA(2);

#pragma unroll
    for (int r = 0; r < 4; ++r) {
        if (r < 3) STAGE_B(r + 1, (r + 1) & 1);   // issue early; latency covered below

        const char* buf = (const char*)Bs + (r & 1) * 16384;
#pragma unroll
        for (int j = 0; j < 4; ++j) {
            const int it = r * 4 + j;
            if (it + 3 < 16) LDA(it + 3);          // 3-deep prefetch, slot (it+3)&3

            const float4* acur = aq[it & 3];
            f16x8 af[2];
#pragma unroll
            for (int m = 0; m < 2; ++m) {
                const float4 v = acur[m];
                f16x8 h;
                h[0] = (_Float16)v.x;
                h[1] = (_Float16)fmaf(ei1, tanh_exp2(fmaf(v.x, k2i, -c2i)), ei0);
                h[2] = (_Float16)v.y;
                h[3] = (_Float16)fmaf(ei1, tanh_exp2(fmaf(v.y, k2i, -c2i)), ei0);
                h[4] = (_Float16)v.z;
                h[5] = (_Float16)fmaf(ei1, tanh_exp2(fmaf(v.z, k2i, -c2i)), ei0);
                h[6] = (_Float16)v.w;
                h[7] = (_Float16)fmaf(ei1, tanh_exp2(fmaf(v.w, k2i, -c2i)), ei0);
                af[m] = h;
            }

            f16x8 bf[4];
#pragma unroll
            for (int n = 0; n < 4; ++n) {
                const int rr   = n * 16 + lr;
                const int phys = (j * 4 + lg) ^ lr;     // rr&15 == lr
                bf[n] = *(const f16x8*)(buf + rr * 256 + phys * 16);
            }

#pragma unroll
            for (int m = 0; m < 2; ++m)
#pragma unroll
                for (int n = 0; n < 4; ++n)
                    acc[m][n] = __builtin_amdgcn_mfma_f32_16x16x32_f16(
                        af[m], bf[n], acc[m][n], 0, 0, 0);
        }

        if (r < 3) {
            // B(r+1) had ~4 iterations of compute to land; drain + publish.
            asm volatile("s_waitcnt vmcnt(0)" ::: "memory");
            __builtin_amdgcn_sched_barrier(0);
            __builtin_amdgcn_s_barrier();
        }
    }
#undef LDA
#undef STAGE_B

    // ---- epilogue: z = acc + bias ; out = ptanh_act(z) ----
    const float ea0 = eta_act[0], ea1 = eta_act[1];
    const float k2a = 2.0f * eta_act[3] * LOG2E_;
    const float c2a = 2.0f * eta_act[2] * eta_act[3] * LOG2E_;

    float bc[4];
#pragma unroll
    for (int n = 0; n < 4; ++n) bc[n] = bias[col0 + n * 16 + lr];

#pragma unroll
    for (int m = 0; m < 2; ++m) {
        const int rgb = row0 + m * 16 + lg * 4;
#pragma unroll
        for (int n = 0; n < 4; ++n) {
            const int cg = col0 + n * 16 + lr;
#pragma unroll
            for (int j = 0; j < 4; ++j) {
                const float z = acc[m][n][j] + bc[n];
                out[(size_t)(rgb + j) * 256 + cg] =
                    fmaf(ea1, tanh_exp2(fmaf(z, k2a, -c2a)), ea0);
            }
        }
    }
}

// ---------------------------------------------------------------------------
extern "C" void kernel_launch(void* const* d_in, const int* in_sizes, int n_in,
                              void* d_out, int out_size, void* d_ws, size_t ws_size,
                              hipStream_t stream) {
    (void)in_sizes; (void)n_in; (void)out_size; (void)ws_size;
    const float* a       = (const float*)d_in[0];
    const float* theta   = (const float*)d_in[1];
    const float* eta_act = (const float*)d_in[2];
    const float* eta_inv = (const float*)d_in[3];
    float* out = (float*)d_out;

    _Float16* W2t  = (_Float16*)d_ws;                        // 256 KiB
    float*    bias = (float*)((char*)d_ws + 256 * 512 * 2);  // 1 KiB

    prep_weights<<<16, 256, 0, stream>>>(theta, eta_inv, W2t, bias);
    plax_gemm<<<1024, 256, 0, stream>>>(a, W2t, bias, eta_act, eta_inv, out);
}